// Round 9
// baseline (268.576 us; speedup 1.0000x reference)
//
#include <hip/hip_runtime.h>
#include <hip/hip_bf16.h>

#define T_TOKENS 2048
#define HID 1024
#define ISZ 1408
#define NEXP 8
#define RROWS 5120   // 4096 rows + per-expert 128-alignment padding

typedef __bf16 bf16x8 __attribute__((ext_vector_type(8)));
typedef __bf16 bf16x4 __attribute__((ext_vector_type(4)));
typedef float  f32x4  __attribute__((ext_vector_type(4)));
typedef float  f32x16 __attribute__((ext_vector_type(16)));

__device__ __forceinline__ void gload16(const void* g, void* l) {
    __builtin_amdgcn_global_load_lds(
        (const __attribute__((address_space(1))) void*)g,
        (__attribute__((address_space(3))) void*)l,
        16, 0, 0);
}

// counted-vmcnt barrier: newest N loads may stay in flight; everything older done.
#define PIPE_BARRIER(N)                                              \
    asm volatile("s_waitcnt vmcnt(" #N ") lgkmcnt(0)" ::: "memory"); \
    __builtin_amdgcn_sched_barrier(0);                               \
    __builtin_amdgcn_s_barrier();                                    \
    __builtin_amdgcn_sched_barrier(0);

// ---------------- Router: one wave per token ----------------
__global__ __launch_bounds__(256) void router_kernel(
    const float* __restrict__ x, const float* __restrict__ gw,
    int* __restrict__ sel, float* __restrict__ wt, int* __restrict__ counts)
{
    __shared__ float sgw[HID * NEXP];  // 32 KB
    for (int i = threadIdx.x; i < HID * NEXP; i += 256) sgw[i] = gw[i];
    __syncthreads();

    const int wave = threadIdx.x >> 6;
    const int lane = threadIdx.x & 63;
    const int t = blockIdx.x * 4 + wave;
    const float* xr = x + (size_t)t * HID;

    const int e = lane & 7;        // expert
    const int c = lane >> 3;       // chunk 0..7 (128 h each)
    float acc = 0.f;
    #pragma unroll 4
    for (int h = c * 128; h < c * 128 + 128; ++h)
        acc += xr[h] * sgw[h * NEXP + e];
    acc += __shfl_xor(acc, 8);
    acc += __shfl_xor(acc, 16);
    acc += __shfl_xor(acc, 32);
    float m = acc;
    #pragma unroll
    for (int d = 1; d < 8; d <<= 1) m = fmaxf(m, __shfl_xor(m, d));
    float p = expf(acc - m);
    float s = p;
    #pragma unroll
    for (int d = 1; d < 8; d <<= 1) s += __shfl_xor(s, d);
    p /= s;
    float p1 = p; int e1 = e;
    #pragma unroll
    for (int d = 1; d < 8; d <<= 1) {
        float op = __shfl_xor(p1, d); int oe = __shfl_xor(e1, d);
        if (op > p1 || (op == p1 && oe < e1)) { p1 = op; e1 = oe; }
    }
    float pm = (e == e1) ? -1.0f : p;
    float p2 = pm; int e2 = e;
    #pragma unroll
    for (int d = 1; d < 8; d <<= 1) {
        float op = __shfl_xor(p2, d); int oe = __shfl_xor(e2, d);
        if (op > p2 || (op == p2 && oe < e2)) { p2 = op; e2 = oe; }
    }
    if (lane == 0) {
        float inv = 1.0f / (p1 + p2);
        sel[t * 2 + 0] = e1; sel[t * 2 + 1] = e2;
        wt[t * 2 + 0] = p1 * inv; wt[t * 2 + 1] = p2 * inv;
        atomicAdd(&counts[e1], 1); atomicAdd(&counts[e2], 1);
    }
}

__global__ void scan_kernel(const int* __restrict__ counts, int* __restrict__ offs,
                            int* __restrict__ ncnt, int* __restrict__ cursor)
{
    if (threadIdx.x == 0 && blockIdx.x == 0) {
        int cur = 0;
        for (int e = 0; e < NEXP; ++e) {
            offs[e] = cur;
            int n = (counts[e] + 127) & ~127;   // 128-row tile alignment
            ncnt[e] = n;
            cursor[e] = 0;
            cur += n;
        }
    }
}

__global__ __launch_bounds__(256) void assign_kernel(
    const int* __restrict__ sel, const float* __restrict__ wt,
    const int* __restrict__ offs, int* __restrict__ cursor,
    int* __restrict__ rtok, float* __restrict__ rwt, int* __restrict__ tok2row)
{
    int t = blockIdx.x * 256 + threadIdx.x;
    if (t >= T_TOKENS) return;
    #pragma unroll
    for (int k = 0; k < 2; ++k) {
        int e = sel[t * 2 + k];
        int pos = atomicAdd(&cursor[e], 1);
        int row = offs[e] + pos;
        rtok[row] = t;
        rwt[row] = wt[t * 2 + k];
        tok2row[t * 2 + k] = row;
    }
}

// ---------------- Gather compacted token rows, fp32 -> bf16 ----------------
__global__ __launch_bounds__(256) void gather_kernel(
    const float* __restrict__ x, const int* __restrict__ rtok, __bf16* __restrict__ xg)
{
    const int row = blockIdx.x;
    const int tid = threadIdx.x;
    const int tok = rtok[row];
    bf16x4 o;
    if (tok >= 0) {
        float4 v = *(const float4*)(x + (size_t)tok * HID + tid * 4);
        o[0] = (__bf16)v.x; o[1] = (__bf16)v.y; o[2] = (__bf16)v.z; o[3] = (__bf16)v.w;
    } else {
        o[0] = (__bf16)0.f; o[1] = (__bf16)0.f; o[2] = (__bf16)0.f; o[3] = (__bf16)0.f;
    }
    *(bf16x4*)(xg + (size_t)row * HID + tid * 4) = o;
}

// ---------------- Fused transpose+convert for all 3 weights ----------------
__global__ __launch_bounds__(256) void tcvt_all_kernel(
    const float* __restrict__ wg, const float* __restrict__ wu, const float* __restrict__ wd,
    __bf16* __restrict__ wgT, __bf16* __restrict__ wuT, __bf16* __restrict__ wdT)
{
    const int z = blockIdx.z;
    const int e = z & 7;
    const float* in;
    __bf16* out;
    int R, C, r0, c0;
    if (z < 16) {
        R = HID; C = ISZ;
        r0 = blockIdx.y * 64; c0 = blockIdx.x * 64;
        in  = (z < 8 ? wg : wu)  + (size_t)e * R * C;
        out = (z < 8 ? wgT : wuT) + (size_t)e * R * C;
    } else {
        R = ISZ; C = HID;
        r0 = blockIdx.x * 64; c0 = blockIdx.y * 64;
        in  = wd  + (size_t)e * R * C;
        out = wdT + (size_t)e * R * C;
    }
    __shared__ float t[64][65];
    const int tid = threadIdx.x;
    const int lr  = tid >> 4;
    const int lc4 = (tid & 15) * 4;
    #pragma unroll
    for (int p = 0; p < 4; ++p) {
        float4 v = *(const float4*)(in + (size_t)(r0 + p * 16 + lr) * C + c0 + lc4);
        t[p * 16 + lr][lc4 + 0] = v.x;
        t[p * 16 + lr][lc4 + 1] = v.y;
        t[p * 16 + lr][lc4 + 2] = v.z;
        t[p * 16 + lr][lc4 + 3] = v.w;
    }
    __syncthreads();
    #pragma unroll
    for (int p = 0; p < 4; ++p) {
        int oc = p * 16 + lr;
        bf16x4 w;
        #pragma unroll
        for (int j = 0; j < 4; ++j) w[j] = (__bf16)t[lc4 + j][oc];
        *(bf16x4*)(out + (size_t)(c0 + oc) * R + r0 + lc4) = w;
    }
}

// ---------------- FFN1: inter = silu(xg@WgT') * (xg@WuT') ----------------
// BM=128, BN=64(G)+64(U), BK=64, 32x32x16 MFMA, 4 waves: (wr,wc) owns rows wr*64,
// cols wc*32 of BOTH G and U. 3-buf 2-ahead counted-vmcnt pipeline, 8-chunk XOR swizzle.
__global__ __launch_bounds__(256) void ffn1_kernel(
    const __bf16* __restrict__ xg,
    const __bf16* __restrict__ wgT, const __bf16* __restrict__ wuT,
    const int* __restrict__ offs, const int* __restrict__ ncnt,
    __bf16* __restrict__ inter)
{
    // grid 5632 = 22 stripes x 8 e x 32 rt; XCD chunks of 704
    const int n  = blockIdx.x;
    const int nn = (n & 7) * 704 + (n >> 3);
    const int i0 = (nn >> 8) * 64;          // stripe 0..21, 64 cols of G (and U)
    const int rem = nn & 255;
    const int e  = rem >> 5;
    const int rt = rem & 31;
    if (rt * 128 >= ncnt[e]) return;
    const int rowbase = offs[e] + rt * 128;

    __shared__ __align__(16) __bf16 sA[3][128][64];  // 48 KB
    __shared__ __align__(16) __bf16 sG[3][64][64];   // 24 KB
    __shared__ __align__(16) __bf16 sU[3][64][64];   // 24 KB

    const int tid  = threadIdx.x;
    const int lane = tid & 63;
    const int wid  = tid >> 6;
    const int wr = wid >> 1, wc = wid & 1;
    const int l31 = lane & 31;
    const int kg  = lane >> 5;          // k-group 0/1

    // staging lanes: row-in-8 = lane>>3, chunk = lane&7; source chunk XORed (involution)
    const int r8 = lane >> 3;
    const int cz = ((lane & 7) ^ r8) * 8;    // element offset
    const __bf16* A0 = xg + (size_t)(rowbase + wid * 32 + r8) * HID + cz;
    const size_t wbase = (size_t)e * ISZ * HID + (size_t)(i0 + wid * 16 + r8) * HID + cz;
    const __bf16* G0 = wgT + wbase;
    const __bf16* U0 = wuT + wbase;

    f32x16 accG[2], accU[2];
    #pragma unroll
    for (int m = 0; m < 2; ++m) {
        #pragma unroll
        for (int r = 0; r < 16; ++r) { accG[m][r] = 0.f; accU[m][r] = 0.f; }
    }

    auto stage = [&](int b, int k0) {   // 8 gload16 per wave
        #pragma unroll
        for (int j = 0; j < 4; ++j)
            gload16(A0 + k0 + (size_t)(8 * j) * HID, &sA[b][wid * 32 + 8 * j][0]);
        #pragma unroll
        for (int j = 0; j < 2; ++j) {
            gload16(G0 + k0 + (size_t)(8 * j) * HID, &sG[b][wid * 16 + 8 * j][0]);
            gload16(U0 + k0 + (size_t)(8 * j) * HID, &sU[b][wid * 16 + 8 * j][0]);
        }
    };
    auto compute = [&](int b) {
        #pragma unroll
        for (int s = 0; s < 4; ++s) {
            const int ch = ((2 * s + kg) ^ (lane & 7)) * 8;
            bf16x8 a0 = *(const bf16x8*)&sA[b][wr * 64 + l31][ch];
            bf16x8 a1 = *(const bf16x8*)&sA[b][wr * 64 + 32 + l31][ch];
            bf16x8 g_ = *(const bf16x8*)&sG[b][wc * 32 + l31][ch];
            bf16x8 u_ = *(const bf16x8*)&sU[b][wc * 32 + l31][ch];
            __builtin_amdgcn_s_setprio(1);
            accG[0] = __builtin_amdgcn_mfma_f32_32x32x16_bf16(a0, g_, accG[0], 0, 0, 0);
            accG[1] = __builtin_amdgcn_mfma_f32_32x32x16_bf16(a1, g_, accG[1], 0, 0, 0);
            accU[0] = __builtin_amdgcn_mfma_f32_32x32x16_bf16(a0, u_, accU[0], 0, 0, 0);
            accU[1] = __builtin_amdgcn_mfma_f32_32x32x16_bf16(a1, u_, accU[1], 0, 0, 0);
            __builtin_amdgcn_s_setprio(0);
        }
    };

    const int nIter = HID / 64;   // 16
    stage(0, 0);
    stage(1, 64);
    PIPE_BARRIER(8)
    int i = 0;
    #define FFN1_STEP(BUF) {                                   \
        int ks = (i + 2) * 64; if (ks >= HID) ks = 0;          \
        stage(((BUF) + 2) % 3, ks);                            \
        compute(BUF);                                          \
        PIPE_BARRIER(8)                                        \
        ++i; }
    #pragma unroll 1
    for (int grp = 0; grp < 5; ++grp) {   // 15 iters
        FFN1_STEP(0) FFN1_STEP(1) FFN1_STEP(2)
    }
    FFN1_STEP(0)                           // i=15, buf 0
    #undef FFN1_STEP

    // epilogue: silu(G)*U -> bf16 inter (D: col = lane&31, row = (reg&3)+8*(reg>>2)+4*kg)
    #pragma unroll
    for (int m = 0; m < 2; ++m) {
        const int base_row = rowbase + wr * 64 + m * 32;
        #pragma unroll
        for (int r = 0; r < 16; ++r) {
            float g = accG[m][r];
            float u = accU[m][r];
            float v = g / (1.0f + __expf(-g)) * u;
            int row = base_row + (r & 3) + 8 * (r >> 2) + 4 * kg;
            inter[(size_t)row * ISZ + i0 + wc * 32 + l31] = (__bf16)v;
        }
    }
}

// ---------------- FFN2: y[row] = rwt[row] * (inter[row] @ WdT')  (no atomics) ----------------
// BM=128, BN=128, BK=64, 32x32x16 MFMA, 4 waves (wr,wc) each 64x64. Same pipeline/swizzle.
__global__ __launch_bounds__(256) void ffn2_kernel(
    const __bf16* __restrict__ inter, const __bf16* __restrict__ wdT,
    const float* __restrict__ rwt,
    const int* __restrict__ offs, const int* __restrict__ ncnt,
    float* __restrict__ y)
{
    // grid 2048 = 8 stripes x 8 e x 32 rt; XCD chunks of 256
    const int n  = blockIdx.x;
    const int nn = (n & 7) * 256 + (n >> 3);
    const int n0 = (nn >> 8) * 128;         // stripe 0..7, 128 out cols
    const int rem = nn & 255;
    const int e  = rem >> 5;
    const int rt = rem & 31;
    if (rt * 128 >= ncnt[e]) return;
    const int rowbase = offs[e] + rt * 128;

    __shared__ __align__(16) __bf16 sA[3][128][64];  // 48 KB
    __shared__ __align__(16) __bf16 sB[3][128][64];  // 48 KB

    const int tid  = threadIdx.x;
    const int lane = tid & 63;
    const int wid  = tid >> 6;
    const int wr = wid >> 1, wc = wid & 1;
    const int l31 = lane & 31;
    const int kg  = lane >> 5;

    const int r8 = lane >> 3;
    const int cz = ((lane & 7) ^ r8) * 8;
    const __bf16* A0 = inter + (size_t)(rowbase + wid * 32 + r8) * ISZ + cz;
    const __bf16* B0 = wdT + (size_t)e * HID * ISZ + (size_t)(n0 + wid * 32 + r8) * ISZ + cz;

    f32x16 acc[2][2];
    #pragma unroll
    for (int m = 0; m < 2; ++m)
        #pragma unroll
        for (int q = 0; q < 2; ++q)
            #pragma unroll
            for (int r = 0; r < 16; ++r) acc[m][q][r] = 0.f;

    auto stage = [&](int b, int k0) {   // 8 gload16 per wave
        #pragma unroll
        for (int j = 0; j < 4; ++j) {
            gload16(A0 + k0 + (size_t)(8 * j) * ISZ, &sA[b][wid * 32 + 8 * j][0]);
            gload16(B0 + k0 + (size_t)(8 * j) * ISZ, &sB[b][wid * 32 + 8 * j][0]);
        }
    };
    auto compute = [&](int b) {
        #pragma unroll
        for (int s = 0; s < 4; ++s) {
            const int ch = ((2 * s + kg) ^ (lane & 7)) * 8;
            bf16x8 a0 = *(const bf16x8*)&sA[b][wr * 64 + l31][ch];
            bf16x8 a1 = *(const bf16x8*)&sA[b][wr * 64 + 32 + l31][ch];
            bf16x8 b0 = *(const bf16x8*)&sB[b][wc * 64 + l31][ch];
            bf16x8 b1 = *(const bf16x8*)&sB[b][wc * 64 + 32 + l31][ch];
            __builtin_amdgcn_s_setprio(1);
            acc[0][0] = __builtin_amdgcn_mfma_f32_32x32x16_bf16(a0, b0, acc[0][0], 0, 0, 0);
            acc[0][1] = __builtin_amdgcn_mfma_f32_32x32x16_bf16(a0, b1, acc[0][1], 0, 0, 0);
            acc[1][0] = __builtin_amdgcn_mfma_f32_32x32x16_bf16(a1, b0, acc[1][0], 0, 0, 0);
            acc[1][1] = __builtin_amdgcn_mfma_f32_32x32x16_bf16(a1, b1, acc[1][1], 0, 0, 0);
            __builtin_amdgcn_s_setprio(0);
        }
    };

    const int nIter = ISZ / 64;   // 22
    stage(0, 0);
    stage(1, 64);
    PIPE_BARRIER(8)
    int i = 0;
    #define FFN2_STEP(BUF) {                                   \
        int ks = (i + 2) * 64; if (ks >= ISZ) ks = 0;          \
        stage(((BUF) + 2) % 3, ks);                            \
        compute(BUF);                                          \
        PIPE_BARRIER(8)                                        \
        ++i; }
    #pragma unroll 1
    for (int grp = 0; grp < 7; ++grp) {   // 21 iters
        FFN2_STEP(0) FFN2_STEP(1) FFN2_STEP(2)
    }
    FFN2_STEP(0)                           // i=21, buf 0
    #undef FFN2_STEP

    #pragma unroll
    for (int m = 0; m < 2; ++m) {
        const int base_row = rowbase + wr * 64 + m * 32;
        #pragma unroll
        for (int q = 0; q < 2; ++q) {
            const int col = n0 + wc * 64 + q * 32 + l31;
            #pragma unroll
            for (int r = 0; r < 16; ++r) {
                int row = base_row + (r & 3) + 8 * (r >> 2) + 4 * kg;
                y[(size_t)row * HID + col] = rwt[row] * acc[m][q][r];
            }
        }
    }
}

// ---------------- Combine: out[t] = y[row0(t)] + y[row1(t)] ----------------
__global__ __launch_bounds__(256) void combine_kernel(
    const float* __restrict__ y, const int* __restrict__ tok2row, float* __restrict__ out)
{
    const int idx = blockIdx.x * 256 + threadIdx.x;
    const int t = idx >> 8;
    const int c = (idx & 255) * 4;
    const int r0 = tok2row[t * 2];
    const int r1 = tok2row[t * 2 + 1];
    float4 a = *(const float4*)(y + (size_t)r0 * HID + c);
    float4 b = *(const float4*)(y + (size_t)r1 * HID + c);
    float4 o = {a.x + b.x, a.y + b.y, a.z + b.z, a.w + b.w};
    *(float4*)(out + (size_t)t * HID + c) = o;
}

extern "C" void kernel_launch(void* const* d_in, const int* in_sizes, int n_in,
                              void* d_out, int out_size, void* d_ws, size_t ws_size,
                              hipStream_t stream) {
    const float* x  = (const float*)d_in[0];
    const float* gw = (const float*)d_in[1];
    const float* wg = (const float*)d_in[2];
    const float* wu = (const float*)d_in[3];
    const float* wd = (const float*)d_in[4];
    float* out = (float*)d_out;

    char* ws = (char*)d_ws;
    int*    counts  = (int*)(ws + 0);
    int*    cursor  = (int*)(ws + 32);
    int*    offs    = (int*)(ws + 64);
    int*    ncnt    = (int*)(ws + 96);
    int*    sel     = (int*)(ws + 128);
    float*  wtp     = (float*)(ws + 16512);
    int*    rtok    = (int*)(ws + 32896);
    float*  rwt     = (float*)(ws + 53376);
    int*    tok2row = (int*)(ws + 73856);
    __bf16* xg      = (__bf16*)(ws + 90240);            // 10.49 MB
    __bf16* inter   = (__bf16*)(ws + 10576000);         // 14.42 MB
    __bf16* wgT     = (__bf16*)(ws + 24993920);         // 23.07 MB
    __bf16* wuT     = (__bf16*)(ws + 48062592);         // 23.07 MB
    __bf16* wdT     = (__bf16*)(ws + 71131264);         // 23.07 MB
    float*  y       = (float*)wgT;                      // alias: wgT dead after ffn1

    hipMemsetAsync(counts, 0, 32, stream);
    hipMemsetAsync(rtok, 0xFF, RROWS * 4, stream);

    tcvt_all_kernel<<<dim3(ISZ / 64, HID / 64, 24), 256, 0, stream>>>(wg, wu, wd, wgT, wuT, wdT);

    router_kernel<<<T_TOKENS / 4, 256, 0, stream>>>(x, gw, sel, wtp, counts);
    scan_kernel<<<1, 64, 0, stream>>>(counts, offs, ncnt, cursor);
    assign_kernel<<<(T_TOKENS + 255) / 256, 256, 0, stream>>>(sel, wtp, offs, cursor, rtok, rwt, tok2row);
    gather_kernel<<<RROWS, 256, 0, stream>>>(x, rtok, xg);

    ffn1_kernel<<<22 * 256, 256, 0, stream>>>(xg, wgT, wuT, offs, ncnt, inter);  // 5632
    ffn2_kernel<<<8 * 256, 256, 0, stream>>>(inter, wdT, rwt, offs, ncnt, y);    // 2048
    combine_kernel<<<(T_TOKENS * HID / 4) / 256, 256, 0, stream>>>(y, tok2row, out);
}

// Round 10
// 219.891 us; speedup vs baseline: 1.2214x; 1.2214x over previous
//
#include <hip/hip_runtime.h>
#include <hip/hip_bf16.h>

#define T_TOKENS 2048
#define HID 1024
#define ISZ 1408
#define NEXP 8
#define RROWS 5120   // 4096 rows + per-expert 128-alignment padding

typedef __bf16 bf16x8 __attribute__((ext_vector_type(8)));
typedef __bf16 bf16x4 __attribute__((ext_vector_type(4)));
typedef float  f32x4  __attribute__((ext_vector_type(4)));
typedef float  f32x16 __attribute__((ext_vector_type(16)));

__device__ __forceinline__ void gload16(const void* g, void* l) {
    __builtin_amdgcn_global_load_lds(
        (const __attribute__((address_space(1))) void*)g,
        (__attribute__((address_space(3))) void*)l,
        16, 0, 0);
}

// drain barrier: all loads landed, all LDS reads done.
#define PIPE_BARRIER()                                               \
    asm volatile("s_waitcnt vmcnt(0) lgkmcnt(0)" ::: "memory");      \
    __builtin_amdgcn_sched_barrier(0);                               \
    __builtin_amdgcn_s_barrier();                                    \
    __builtin_amdgcn_sched_barrier(0);

// ---------------- Router: one wave per token; also converts x -> bf16 xb ----------------
__global__ __launch_bounds__(256) void router_kernel(
    const float* __restrict__ x, const float* __restrict__ gw,
    int* __restrict__ sel, float* __restrict__ wt, int* __restrict__ counts,
    __bf16* __restrict__ xb)
{
    __shared__ float sgw[HID * NEXP];  // 32 KB
    for (int i = threadIdx.x; i < HID * NEXP; i += 256) sgw[i] = gw[i];
    __syncthreads();

    const int wave = threadIdx.x >> 6;
    const int lane = threadIdx.x & 63;
    const int t = blockIdx.x * 4 + wave;
    const float* xr = x + (size_t)t * HID;

    // convert this token's row to bf16 (lane handles 16 elems)
    {
        const int c0 = lane * 16;
        float4 v0 = *(const float4*)(xr + c0);
        float4 v1 = *(const float4*)(xr + c0 + 4);
        float4 v2 = *(const float4*)(xr + c0 + 8);
        float4 v3 = *(const float4*)(xr + c0 + 12);
        bf16x8 o0, o1;
        o0[0]=(__bf16)v0.x; o0[1]=(__bf16)v0.y; o0[2]=(__bf16)v0.z; o0[3]=(__bf16)v0.w;
        o0[4]=(__bf16)v1.x; o0[5]=(__bf16)v1.y; o0[6]=(__bf16)v1.z; o0[7]=(__bf16)v1.w;
        o1[0]=(__bf16)v2.x; o1[1]=(__bf16)v2.y; o1[2]=(__bf16)v2.z; o1[3]=(__bf16)v2.w;
        o1[4]=(__bf16)v3.x; o1[5]=(__bf16)v3.y; o1[6]=(__bf16)v3.z; o1[7]=(__bf16)v3.w;
        *(bf16x8*)(xb + (size_t)t * HID + c0) = o0;
        *(bf16x8*)(xb + (size_t)t * HID + c0 + 8) = o1;
    }

    const int e = lane & 7;        // expert
    const int c = lane >> 3;       // chunk 0..7 (128 h each)
    float acc = 0.f;
    #pragma unroll 4
    for (int h = c * 128; h < c * 128 + 128; ++h)
        acc += xr[h] * sgw[h * NEXP + e];
    acc += __shfl_xor(acc, 8);
    acc += __shfl_xor(acc, 16);
    acc += __shfl_xor(acc, 32);
    float m = acc;
    #pragma unroll
    for (int d = 1; d < 8; d <<= 1) m = fmaxf(m, __shfl_xor(m, d));
    float p = expf(acc - m);
    float s = p;
    #pragma unroll
    for (int d = 1; d < 8; d <<= 1) s += __shfl_xor(s, d);
    p /= s;
    float p1 = p; int e1 = e;
    #pragma unroll
    for (int d = 1; d < 8; d <<= 1) {
        float op = __shfl_xor(p1, d); int oe = __shfl_xor(e1, d);
        if (op > p1 || (op == p1 && oe < e1)) { p1 = op; e1 = oe; }
    }
    float pm = (e == e1) ? -1.0f : p;
    float p2 = pm; int e2 = e;
    #pragma unroll
    for (int d = 1; d < 8; d <<= 1) {
        float op = __shfl_xor(p2, d); int oe = __shfl_xor(e2, d);
        if (op > p2 || (op == p2 && oe < e2)) { p2 = op; e2 = oe; }
    }
    if (lane == 0) {
        float inv = 1.0f / (p1 + p2);
        sel[t * 2 + 0] = e1; sel[t * 2 + 1] = e2;
        wt[t * 2 + 0] = p1 * inv; wt[t * 2 + 1] = p2 * inv;
        atomicAdd(&counts[e1], 1); atomicAdd(&counts[e2], 1);
    }
}

__global__ void scan_kernel(const int* __restrict__ counts, int* __restrict__ offs,
                            int* __restrict__ ncnt, int* __restrict__ cursor)
{
    if (threadIdx.x == 0 && blockIdx.x == 0) {
        int cur = 0;
        for (int e = 0; e < NEXP; ++e) {
            offs[e] = cur;
            int n = (counts[e] + 127) & ~127;   // 128-row tile alignment
            ncnt[e] = n;
            cursor[e] = 0;
            cur += n;
        }
    }
}

__global__ __launch_bounds__(256) void assign_kernel(
    const int* __restrict__ sel, const float* __restrict__ wt,
    const int* __restrict__ offs, int* __restrict__ cursor,
    int* __restrict__ rtok, float* __restrict__ rwt, int* __restrict__ tok2row)
{
    int t = blockIdx.x * 256 + threadIdx.x;
    if (t >= T_TOKENS) return;
    #pragma unroll
    for (int k = 0; k < 2; ++k) {
        int e = sel[t * 2 + k];
        int pos = atomicAdd(&cursor[e], 1);
        int row = offs[e] + pos;
        rtok[row] = t;
        rwt[row] = wt[t * 2 + k];
        tok2row[t * 2 + k] = row;
    }
}

// ---------------- Fused transpose+convert for all 3 weights ----------------
__global__ __launch_bounds__(256) void tcvt_all_kernel(
    const float* __restrict__ wg, const float* __restrict__ wu, const float* __restrict__ wd,
    __bf16* __restrict__ wgT, __bf16* __restrict__ wuT, __bf16* __restrict__ wdT)
{
    const int z = blockIdx.z;
    const int e = z & 7;
    const float* in;
    __bf16* out;
    int R, C, r0, c0;
    if (z < 16) {
        R = HID; C = ISZ;
        r0 = blockIdx.y * 64; c0 = blockIdx.x * 64;
        in  = (z < 8 ? wg : wu)  + (size_t)e * R * C;
        out = (z < 8 ? wgT : wuT) + (size_t)e * R * C;
    } else {
        R = ISZ; C = HID;
        r0 = blockIdx.x * 64; c0 = blockIdx.y * 64;
        in  = wd  + (size_t)e * R * C;
        out = wdT + (size_t)e * R * C;
    }
    __shared__ float t[64][65];
    const int tid = threadIdx.x;
    const int lr  = tid >> 4;
    const int lc4 = (tid & 15) * 4;
    #pragma unroll
    for (int p = 0; p < 4; ++p) {
        float4 v = *(const float4*)(in + (size_t)(r0 + p * 16 + lr) * C + c0 + lc4);
        t[p * 16 + lr][lc4 + 0] = v.x;
        t[p * 16 + lr][lc4 + 1] = v.y;
        t[p * 16 + lr][lc4 + 2] = v.z;
        t[p * 16 + lr][lc4 + 3] = v.w;
    }
    __syncthreads();
    #pragma unroll
    for (int p = 0; p < 4; ++p) {
        int oc = p * 16 + lr;
        bf16x4 w;
        #pragma unroll
        for (int j = 0; j < 4; ++j) w[j] = (__bf16)t[lc4 + j][oc];
        *(bf16x4*)(out + (size_t)(c0 + oc) * R + r0 + lc4) = w;
    }
}

// ---------------- FFN1: inter = silu(x@WgT') * (x@WuT') ----------------
// BM=128, BN=64(G)+64(U), BK=64, 32x32x16 MFMA, 4 waves: (wr,wc) owns rows wr*64,
// cols wc*32 of BOTH G and U. 2-buf issue-early pipeline, 8-chunk XOR swizzle,
// A staged straight from token-space xb via per-lane rtok indirection.
__global__ __launch_bounds__(256) void ffn1_kernel(
    const __bf16* __restrict__ xb, const int* __restrict__ rtok,
    const __bf16* __restrict__ wgT, const __bf16* __restrict__ wuT,
    const int* __restrict__ offs, const int* __restrict__ ncnt,
    __bf16* __restrict__ inter)
{
    // grid 5632 = 22 stripes x 8 e x 32 rt; XCD chunks of 704
    const int n  = blockIdx.x;
    const int nn = (n & 7) * 704 + (n >> 3);
    const int i0 = (nn >> 8) * 64;          // stripe 0..21
    const int rem = nn & 255;
    const int e  = rem >> 5;
    const int rt = rem & 31;
    if (rt * 128 >= ncnt[e]) return;
    const int rowbase = offs[e] + rt * 128;

    __shared__ __align__(16) __bf16 sA[2][128][64];  // 32 KB
    __shared__ __align__(16) __bf16 sG[2][64][64];   // 16 KB
    __shared__ __align__(16) __bf16 sU[2][64][64];   // 16 KB

    const int tid  = threadIdx.x;
    const int lane = tid & 63;
    const int wid  = tid >> 6;
    const int wr = wid >> 1, wc = wid & 1;
    const int l31 = lane & 31;
    const int kg  = lane >> 5;          // k-group 0/1

    // staging lanes: row-in-8 = lane>>3, chunk slot = lane&7 holds global chunk (lane&7)^r8
    const int r8 = lane >> 3;
    const int cz = ((lane & 7) ^ r8) * 8;    // element offset
    const __bf16* Aj[4];
    #pragma unroll
    for (int j = 0; j < 4; ++j) {
        int row = rowbase + wid * 32 + 8 * j + r8;
        int tok = rtok[row];
        int src = (tok < 0) ? T_TOKENS : tok;        // pad rows -> zero row
        Aj[j] = xb + (size_t)src * HID + cz;
    }
    const size_t wbase = (size_t)e * ISZ * HID + (size_t)(i0 + wid * 16 + r8) * HID + cz;
    const __bf16* G0 = wgT + wbase;
    const __bf16* U0 = wuT + wbase;

    f32x16 accG[2], accU[2];
    #pragma unroll
    for (int m = 0; m < 2; ++m) {
        #pragma unroll
        for (int r = 0; r < 16; ++r) { accG[m][r] = 0.f; accU[m][r] = 0.f; }
    }

    auto stage = [&](int b, int k0) {   // 8 gload16 per wave
        #pragma unroll
        for (int j = 0; j < 4; ++j)
            gload16(Aj[j] + k0, &sA[b][wid * 32 + 8 * j][0]);
        #pragma unroll
        for (int j = 0; j < 2; ++j) {
            gload16(G0 + k0 + (size_t)(8 * j) * HID, &sG[b][wid * 16 + 8 * j][0]);
            gload16(U0 + k0 + (size_t)(8 * j) * HID, &sU[b][wid * 16 + 8 * j][0]);
        }
    };
    auto compute = [&](int b) {
        #pragma unroll
        for (int s = 0; s < 4; ++s) {
            const int ch = ((2 * s + kg) ^ (lane & 7)) * 8;
            bf16x8 a0 = *(const bf16x8*)&sA[b][wr * 64 + l31][ch];
            bf16x8 a1 = *(const bf16x8*)&sA[b][wr * 64 + 32 + l31][ch];
            bf16x8 g_ = *(const bf16x8*)&sG[b][wc * 32 + l31][ch];
            bf16x8 u_ = *(const bf16x8*)&sU[b][wc * 32 + l31][ch];
            __builtin_amdgcn_s_setprio(1);
            accG[0] = __builtin_amdgcn_mfma_f32_32x32x16_bf16(a0, g_, accG[0], 0, 0, 0);
            accG[1] = __builtin_amdgcn_mfma_f32_32x32x16_bf16(a1, g_, accG[1], 0, 0, 0);
            accU[0] = __builtin_amdgcn_mfma_f32_32x32x16_bf16(a0, u_, accU[0], 0, 0, 0);
            accU[1] = __builtin_amdgcn_mfma_f32_32x32x16_bf16(a1, u_, accU[1], 0, 0, 0);
            __builtin_amdgcn_s_setprio(0);
        }
    };

    const int nIter = HID / 64;   // 16
    stage(0, 0);
    PIPE_BARRIER()
    #pragma unroll 2
    for (int i = 0; i < nIter; ++i) {
        if (i + 1 < nIter) stage((i + 1) & 1, (i + 1) * 64);   // issue-early prefetch
        compute(i & 1);
        PIPE_BARRIER()
    }

    // epilogue: silu(G)*U -> bf16 inter (D: col = lane&31, row = (reg&3)+8*(reg>>2)+4*kg)
    #pragma unroll
    for (int m = 0; m < 2; ++m) {
        const int base_row = rowbase + wr * 64 + m * 32;
        #pragma unroll
        for (int r = 0; r < 16; ++r) {
            float g = accG[m][r];
            float u = accU[m][r];
            float v = g / (1.0f + __expf(-g)) * u;
            int row = base_row + (r & 3) + 8 * (r >> 2) + 4 * kg;
            inter[(size_t)row * ISZ + i0 + wc * 32 + l31] = (__bf16)v;
        }
    }
}

// ---------------- FFN2: y[row] = rwt[row] * (inter[row] @ WdT')  (no atomics) ----------------
// BM=128, BN=128, BK=64, 32x32x16 MFMA, 4 waves (wr,wc) each 64x64. 2-buf issue-early.
__global__ __launch_bounds__(256) void ffn2_kernel(
    const __bf16* __restrict__ inter, const __bf16* __restrict__ wdT,
    const float* __restrict__ rwt,
    const int* __restrict__ offs, const int* __restrict__ ncnt,
    float* __restrict__ y)
{
    // grid 2048 = 8 stripes x 8 e x 32 rt; XCD chunks of 256
    const int n  = blockIdx.x;
    const int nn = (n & 7) * 256 + (n >> 3);
    const int n0 = (nn >> 8) * 128;         // stripe 0..7
    const int rem = nn & 255;
    const int e  = rem >> 5;
    const int rt = rem & 31;
    if (rt * 128 >= ncnt[e]) return;
    const int rowbase = offs[e] + rt * 128;

    __shared__ __align__(16) __bf16 sA[2][128][64];  // 32 KB
    __shared__ __align__(16) __bf16 sB[2][128][64];  // 32 KB

    const int tid  = threadIdx.x;
    const int lane = tid & 63;
    const int wid  = tid >> 6;
    const int wr = wid >> 1, wc = wid & 1;
    const int l31 = lane & 31;
    const int kg  = lane >> 5;

    const int r8 = lane >> 3;
    const int cz = ((lane & 7) ^ r8) * 8;
    const __bf16* A0 = inter + (size_t)(rowbase + wid * 32 + r8) * ISZ + cz;
    const __bf16* B0 = wdT + (size_t)e * HID * ISZ + (size_t)(n0 + wid * 32 + r8) * ISZ + cz;

    f32x16 acc[2][2];
    #pragma unroll
    for (int m = 0; m < 2; ++m)
        #pragma unroll
        for (int q = 0; q < 2; ++q)
            #pragma unroll
            for (int r = 0; r < 16; ++r) acc[m][q][r] = 0.f;

    auto stage = [&](int b, int k0) {   // 8 gload16 per wave
        #pragma unroll
        for (int j = 0; j < 4; ++j) {
            gload16(A0 + k0 + (size_t)(8 * j) * ISZ, &sA[b][wid * 32 + 8 * j][0]);
            gload16(B0 + k0 + (size_t)(8 * j) * ISZ, &sB[b][wid * 32 + 8 * j][0]);
        }
    };
    auto compute = [&](int b) {
        #pragma unroll
        for (int s = 0; s < 4; ++s) {
            const int ch = ((2 * s + kg) ^ (lane & 7)) * 8;
            bf16x8 a0 = *(const bf16x8*)&sA[b][wr * 64 + l31][ch];
            bf16x8 a1 = *(const bf16x8*)&sA[b][wr * 64 + 32 + l31][ch];
            bf16x8 b0 = *(const bf16x8*)&sB[b][wc * 64 + l31][ch];
            bf16x8 b1 = *(const bf16x8*)&sB[b][wc * 64 + 32 + l31][ch];
            __builtin_amdgcn_s_setprio(1);
            acc[0][0] = __builtin_amdgcn_mfma_f32_32x32x16_bf16(a0, b0, acc[0][0], 0, 0, 0);
            acc[0][1] = __builtin_amdgcn_mfma_f32_32x32x16_bf16(a0, b1, acc[0][1], 0, 0, 0);
            acc[1][0] = __builtin_amdgcn_mfma_f32_32x32x16_bf16(a1, b0, acc[1][0], 0, 0, 0);
            acc[1][1] = __builtin_amdgcn_mfma_f32_32x32x16_bf16(a1, b1, acc[1][1], 0, 0, 0);
            __builtin_amdgcn_s_setprio(0);
        }
    };

    const int nIter = ISZ / 64;   // 22
    stage(0, 0);
    PIPE_BARRIER()
    #pragma unroll 2
    for (int i = 0; i < nIter; ++i) {
        if (i + 1 < nIter) stage((i + 1) & 1, (i + 1) * 64);
        compute(i & 1);
        PIPE_BARRIER()
    }

    #pragma unroll
    for (int m = 0; m < 2; ++m) {
        const int base_row = rowbase + wr * 64 + m * 32;
        #pragma unroll
        for (int q = 0; q < 2; ++q) {
            const int col = n0 + wc * 64 + q * 32 + l31;
            #pragma unroll
            for (int r = 0; r < 16; ++r) {
                int row = base_row + (r & 3) + 8 * (r >> 2) + 4 * kg;
                y[(size_t)row * HID + col] = rwt[row] * acc[m][q][r];
            }
        }
    }
}

// ---------------- Combine: out[t] = y[row0(t)] + y[row1(t)] ----------------
__global__ __launch_bounds__(256) void combine_kernel(
    const float* __restrict__ y, const int* __restrict__ tok2row, float* __restrict__ out)
{
    const int idx = blockIdx.x * 256 + threadIdx.x;
    const int t = idx >> 8;
    const int c = (idx & 255) * 4;
    const int r0 = tok2row[t * 2];
    const int r1 = tok2row[t * 2 + 1];
    float4 a = *(const float4*)(y + (size_t)r0 * HID + c);
    float4 b = *(const float4*)(y + (size_t)r1 * HID + c);
    float4 o = {a.x + b.x, a.y + b.y, a.z + b.z, a.w + b.w};
    *(float4*)(out + (size_t)t * HID + c) = o;
}

extern "C" void kernel_launch(void* const* d_in, const int* in_sizes, int n_in,
                              void* d_out, int out_size, void* d_ws, size_t ws_size,
                              hipStream_t stream) {
    const float* x  = (const float*)d_in[0];
    const float* gw = (const float*)d_in[1];
    const float* wg = (const float*)d_in[2];
    const float* wu = (const float*)d_in[3];
    const float* wd = (const float*)d_in[4];
    float* out = (float*)d_out;

    char* ws = (char*)d_ws;
    int*    counts  = (int*)(ws + 0);
    int*    cursor  = (int*)(ws + 32);
    int*    offs    = (int*)(ws + 64);
    int*    ncnt    = (int*)(ws + 96);
    int*    sel     = (int*)(ws + 128);
    float*  wtp     = (float*)(ws + 16512);
    int*    rtok    = (int*)(ws + 32896);
    float*  rwt     = (float*)(ws + 53376);
    int*    tok2row = (int*)(ws + 73856);
    __bf16* xb      = (__bf16*)(ws + 90240);            // (2048+1)*1024 bf16 = 4.2 MB
    __bf16* inter   = (__bf16*)(ws + 10576000);         // 14.42 MB
    __bf16* wgT     = (__bf16*)(ws + 24993920);         // 23.07 MB
    __bf16* wuT     = (__bf16*)(ws + 48062592);         // 23.07 MB
    __bf16* wdT     = (__bf16*)(ws + 71131264);         // 23.07 MB
    float*  y       = (float*)wgT;                      // alias: wgT dead after ffn1

    hipMemsetAsync(counts, 0, 32, stream);
    hipMemsetAsync(rtok, 0xFF, RROWS * 4, stream);
    hipMemsetAsync(xb + (size_t)T_TOKENS * HID, 0, HID * sizeof(__bf16), stream);  // zero row

    tcvt_all_kernel<<<dim3(ISZ / 64, HID / 64, 24), 256, 0, stream>>>(wg, wu, wd, wgT, wuT, wdT);

    router_kernel<<<T_TOKENS / 4, 256, 0, stream>>>(x, gw, sel, wtp, counts, xb);
    scan_kernel<<<1, 64, 0, stream>>>(counts, offs, ncnt, cursor);
    assign_kernel<<<(T_TOKENS + 255) / 256, 256, 0, stream>>>(sel, wtp, offs, cursor, rtok, rwt, tok2row);

    ffn1_kernel<<<22 * 256, 256, 0, stream>>>(xb, rtok, wgT, wuT, offs, ncnt, inter);  // 5632
    ffn2_kernel<<<8 * 256, 256, 0, stream>>>(inter, wdT, rwt, offs, ncnt, y);          // 2048
    combine_kernel<<<(T_TOKENS * HID / 4) / 256, 256, 0, stream>>>(y, tok2row, out);
}